// Round 13
// baseline (38.497 us; speedup 1.0000x reference)
//
#include <hip/hip_runtime.h>
#include <hip/hip_bf16.h>

typedef __bf16 bf16x8 __attribute__((ext_vector_type(8)));
typedef float  f32x4  __attribute__((ext_vector_type(4)));

#define B_ROWS 8192
#define IN_DIM 256
#define OUT_DIM 32
#define NCLS 50
#define INV_T (1.0f / 0.6f)

#define CVT_BLOCKS 1024  // x cvt: 8192*256 / (256*8)
#define GBLOCKS 512      // gemm grid: exactly 2 blocks/CU

__device__ __forceinline__ void gload_lds16(const void* g, void* l) {
    __builtin_amdgcn_global_load_lds(
        (const __attribute__((address_space(1))) void*)g,
        (__attribute__((address_space(3))) void*)l, 16, 0, 0);
}

// prep: blocks [0,50) = W-class blocks (first, so they overlap the cvt
// blocks); blocks [50, 50+1024) convert x f32->bf16.
// W-block: single pass — hold 32 w-values in regs, gamma/alpha, write W'.
__global__ __launch_bounds__(256) void prep(const float* __restrict__ x,
                                            const float* __restrict__ w,
                                            __bf16* __restrict__ xb,
                                            __bf16* __restrict__ wb) {
    __shared__ float wm[4];
    int bid = blockIdx.x;
    if (bid < NCLS) {
        int c = bid;
        int i = threadIdx.x;  // IN index
        const float* wc = w + (size_t)c * OUT_DIM * IN_DIM + i;
        float wv[OUT_DIM];
#pragma unroll
        for (int o = 0; o < OUT_DIM; ++o) wv[o] = wc[o * IN_DIM];
        float gsum = 0.f;
#pragma unroll
        for (int o = 0; o < OUT_DIM; ++o) gsum += fabsf(wv[o]);
        float m = gsum;
#pragma unroll
        for (int s = 1; s < 64; s <<= 1) m = fmaxf(m, __shfl_xor(m, s));
        if ((threadIdx.x & 63) == 0) wm[threadIdx.x >> 6] = m;
        __syncthreads();
        m = fmaxf(fmaxf(wm[0], wm[1]), fmaxf(wm[2], wm[3]));
        float an = __expf((gsum - m) * INV_T);
        __bf16* wo = wb + (size_t)c * OUT_DIM * IN_DIM + i;
#pragma unroll
        for (int o = 0; o < OUT_DIM; ++o)
            wo[o * IN_DIM] = (__bf16)(wv[o] * an);
    } else {
        int i = ((bid - NCLS) * 256 + threadIdx.x) * 8;
        float4 v0 = *reinterpret_cast<const float4*>(x + i);
        float4 v1 = *reinterpret_cast<const float4*>(x + i + 4);
        bf16x8 r;
        r[0] = (__bf16)v0.x; r[1] = (__bf16)v0.y; r[2] = (__bf16)v0.z; r[3] = (__bf16)v0.w;
        r[4] = (__bf16)v1.x; r[5] = (__bf16)v1.y; r[6] = (__bf16)v1.z; r[7] = (__bf16)v1.w;
        *reinterpret_cast<bf16x8*>(xb + i) = r;
    }
}

// GEMM: out[b, c, o] = sum_i xb[b,i]*wb[c,o,i] + bias[c,o]
// Balanced 512 blocks (2/CU); class-pair p owns blocks [ceil(p*512/25),
// ceil((p+1)*512/25)); block j takes 64-row units [j*128/np,(j+1)*128/np).
// W'+bias loaded direct global->pinned regs, FULL vmcnt drain, THEN the A
// pipeline starts — so the counted waits see only A-loads and C-stores:
//   peeled iter0: stage chunk1, vmcnt(8)  (8 = chunk1 loads)
//   iter k>=1:    stage chunk k+1, vmcnt(12) (= 8 next loads + 4 prev stores)
//   last iter:    vmcnt(4) (= prev stores)
// No __syncthreads anywhere: waves fully independent.
// A LDS swizzle (both-sides): phys 16B-slot s of row r holds logical s^r.
__global__ __launch_bounds__(256, 2) void gemm(const __bf16* __restrict__ xb,
                                               const __bf16* __restrict__ wb,
                                               const float* __restrict__ bias,
                                               float* __restrict__ out) {
    __shared__ __align__(16) char lds[4 * 2 * 8192];  // 4 waves * {Abuf0, Abuf1}

    int bid = blockIdx.x;
    int p = (bid * 25) >> 9;                       // class pair 0..24
    int first = (p * GBLOCKS + 24) / 25;
    int next  = ((p + 1) * GBLOCKS + 24) / 25;
    int j = bid - first;
    int np = next - first;
    int u0 = (j * 128) / np;                       // first 64-row unit
    int u1 = ((j + 1) * 128) / np;
    int nch = u1 - u0;                             // 6..7 chunks

    int c0 = p * 2;
    int lane = threadIdx.x & 63;
    int w4 = threadIdx.x >> 6;
    int l15 = lane & 15;
    int g = lane >> 4;
    int s31 = lane & 31;
    int lr = lane >> 5;          // 0/1

    char* Abuf0 = lds + w4 * 16384;
    char* Abuf1 = Abuf0 + 8192;

    // --- W' pair + bias direct global -> regs ---
    const __bf16* wp = wb + ((size_t)c0 * OUT_DIM + l15) * IN_DIM + g * 8;
    bf16x8 W[2][16];
#pragma unroll
    for (int ci = 0; ci < 2; ++ci)
#pragma unroll
        for (int kk = 0; kk < 8; ++kk) {
            W[ci][kk]     = *reinterpret_cast<const bf16x8*>(wp + ci * 32 * IN_DIM + kk * 32);
            W[ci][8 + kk] = *reinterpret_cast<const bf16x8*>(wp + (ci * 32 + 16) * IN_DIM + kk * 32);
        }
    f32x4 bv00 = *reinterpret_cast<const f32x4*>(bias + c0 * OUT_DIM + g * 4);
    f32x4 bv01 = *reinterpret_cast<const f32x4*>(bias + c0 * OUT_DIM + 16 + g * 4);
    f32x4 bv10 = *reinterpret_cast<const f32x4*>(bias + (c0 + 1) * OUT_DIM + g * 4);
    f32x4 bv11 = *reinterpret_cast<const f32x4*>(bias + (c0 + 1) * OUT_DIM + 16 + g * 4);

    // pin W + bias (forces their loads complete HERE; nothing of them
    // remains in the vmcnt stream afterwards)
#pragma unroll
    for (int ci = 0; ci < 2; ++ci)
#pragma unroll
        for (int kk = 0; kk < 16; ++kk)
            asm volatile("" : "+v"(W[ci][kk]));
    asm volatile("" : "+v"(bv00), "+v"(bv01), "+v"(bv10), "+v"(bv11));
    asm volatile("s_waitcnt vmcnt(0)" ::: "memory");
    __builtin_amdgcn_sched_barrier(0);

    // chunk k rows = (u0+k)*64 + w4*16 + [0,16)
    const char* arows = (const char*)(xb + (size_t)(u0 * 64 + w4 * 16) * IN_DIM);
#define STAGE_A(BUF, AP)                                                          \
    _Pragma("unroll") for (int il = 0; il < 8; ++il) {                            \
        int r = 2 * il + lr;                                                      \
        gload_lds16((AP) + (size_t)r * 512 + ((s31 ^ r) * 16),                    \
                    (BUF) + il * 1024);                                           \
    }

    STAGE_A(Abuf0, arows)                          // chunk 0
    float* orow = out + (size_t)(u0 * 64 + w4 * 16 + l15) * (NCLS * OUT_DIM) + c0 * OUT_DIM + g * 4;

#define COMPUTE_STORE(BUF)                                                        \
    {                                                                             \
        f32x4 acc00 = bv00;                                                       \
        f32x4 acc01 = bv01;                                                       \
        f32x4 acc10 = bv10;                                                       \
        f32x4 acc11 = bv11;                                                       \
        _Pragma("unroll") for (int kk = 0; kk < 8; ++kk) {                        \
            int slot = (4 * kk + g) ^ l15;                                        \
            bf16x8 a = *reinterpret_cast<const bf16x8*>((BUF) + (size_t)l15 * 512 + slot * 16); \
            acc00 = __builtin_amdgcn_mfma_f32_16x16x32_bf16(W[0][kk],     a, acc00, 0, 0, 0);   \
            acc01 = __builtin_amdgcn_mfma_f32_16x16x32_bf16(W[0][8 + kk], a, acc01, 0, 0, 0);   \
            acc10 = __builtin_amdgcn_mfma_f32_16x16x32_bf16(W[1][kk],     a, acc10, 0, 0, 0);   \
            acc11 = __builtin_amdgcn_mfma_f32_16x16x32_bf16(W[1][8 + kk], a, acc11, 0, 0, 0);   \
        }                                                                         \
        *reinterpret_cast<f32x4*>(orow) = acc00;                                  \
        *reinterpret_cast<f32x4*>(orow + 16) = acc01;                             \
        *reinterpret_cast<f32x4*>(orow + OUT_DIM) = acc10;                        \
        *reinterpret_cast<f32x4*>(orow + OUT_DIM + 16) = acc11;                   \
        orow += (size_t)64 * (NCLS * OUT_DIM);                                    \
    }

    // --- peeled iter 0 ---
    STAGE_A(Abuf1, arows + 64 * 512)               // chunk 1
    asm volatile("s_waitcnt vmcnt(8)" ::: "memory");   // chunk0 done
    __builtin_amdgcn_sched_barrier(0);
    COMPUTE_STORE(Abuf0)

    char* cur = Abuf1;
    char* nxt = Abuf0;
    const char* anext = arows + 2 * 64 * 512;      // chunk k+1 source at iter k

    for (int k = 1; k < nch; ++k) {
        if (k + 1 < nch) {
            STAGE_A(nxt, anext)
            anext += 64 * 512;
            asm volatile("s_waitcnt vmcnt(12)" ::: "memory");  // chunk k done
        } else {
            asm volatile("s_waitcnt vmcnt(4)" ::: "memory");   // chunk k done
        }
        __builtin_amdgcn_sched_barrier(0);
        COMPUTE_STORE(cur)
        char* t = cur; cur = nxt; nxt = t;
    }
#undef STAGE_A
#undef COMPUTE_STORE
}

extern "C" void kernel_launch(void* const* d_in, const int* in_sizes, int n_in,
                              void* d_out, int out_size, void* d_ws, size_t ws_size,
                              hipStream_t stream) {
    const float* x    = (const float*)d_in[0];
    const float* w    = (const float*)d_in[1];
    const float* bias = (const float*)d_in[2];
    float* out = (float*)d_out;

    __bf16* xb = (__bf16*)d_ws;                      // 8192*256 bf16 = 4 MB
    __bf16* wb = xb + (size_t)B_ROWS * IN_DIM;       // 50*32*256 bf16 = 0.8 MB

    prep<<<NCLS + CVT_BLOCKS, 256, 0, stream>>>(x, w, xb, wb);
    gemm<<<GBLOCKS, 256, 0, stream>>>(xb, wb, bias, out);
}

// Round 14
// 28.163 us; speedup vs baseline: 1.3669x; 1.3669x over previous
//
#include <hip/hip_runtime.h>
#include <hip/hip_bf16.h>

typedef __bf16 bf16x8 __attribute__((ext_vector_type(8)));
typedef float  f32x4  __attribute__((ext_vector_type(4)));

#define B_ROWS 8192
#define IN_DIM 256
#define OUT_DIM 32
#define NCLS 50
#define INV_T (1.0f / 0.6f)

#define CVT_BLOCKS 1024  // x cvt: 8192*256 / (256*8)
#define ROWTILES 16      // 8192 / 512 rows per block
#define NCHUNK 8         // 128 rows/wave / 16

__device__ __forceinline__ void gload_lds16(const void* g, void* l) {
    __builtin_amdgcn_global_load_lds(
        (const __attribute__((address_space(1))) void*)g,
        (__attribute__((address_space(3))) void*)l, 16, 0, 0);
}

// prep (single launch): blocks [0,50) = W-class blocks (first, so they
// overlap under the cvt blocks); blocks [50,1074) convert x f32->bf16.
// W-block: single pass — 32 w-values in regs, gamma/alpha, write W'.
__global__ __launch_bounds__(256) void prep(const float* __restrict__ x,
                                            const float* __restrict__ w,
                                            __bf16* __restrict__ xb,
                                            __bf16* __restrict__ wb) {
    __shared__ float wm[4];
    int bid = blockIdx.x;
    if (bid < NCLS) {
        int c = bid;
        int i = threadIdx.x;  // IN index
        const float* wc = w + (size_t)c * OUT_DIM * IN_DIM + i;
        float wv[OUT_DIM];
#pragma unroll
        for (int o = 0; o < OUT_DIM; ++o) wv[o] = wc[o * IN_DIM];
        float gsum = 0.f;
#pragma unroll
        for (int o = 0; o < OUT_DIM; ++o) gsum += fabsf(wv[o]);
        float m = gsum;
#pragma unroll
        for (int s = 1; s < 64; s <<= 1) m = fmaxf(m, __shfl_xor(m, s));
        if ((threadIdx.x & 63) == 0) wm[threadIdx.x >> 6] = m;
        __syncthreads();
        m = fmaxf(fmaxf(wm[0], wm[1]), fmaxf(wm[2], wm[3]));
        float an = __expf((gsum - m) * INV_T);
        __bf16* wo = wb + (size_t)c * OUT_DIM * IN_DIM + i;
#pragma unroll
        for (int o = 0; o < OUT_DIM; ++o)
            wo[o * IN_DIM] = (__bf16)(wv[o] * an);
    } else {
        int i = ((bid - NCLS) * 256 + threadIdx.x) * 8;
        float4 v0 = *reinterpret_cast<const float4*>(x + i);
        float4 v1 = *reinterpret_cast<const float4*>(x + i + 4);
        bf16x8 r;
        r[0] = (__bf16)v0.x; r[1] = (__bf16)v0.y; r[2] = (__bf16)v0.z; r[3] = (__bf16)v0.w;
        r[4] = (__bf16)v1.x; r[5] = (__bf16)v1.y; r[6] = (__bf16)v1.z; r[7] = (__bf16)v1.w;
        *reinterpret_cast<bf16x8*>(xb + i) = r;
    }
}

// GEMM (r9 verbatim — proven 30.7us config):
// out[b, c, o] = sum_i xb[b,i]*wb[c,o,i] + bias[c,o]
// grid = 25 class-PAIRS * 16 row-tiles; block = 4 waves, 512 rows, 2 classes.
// W' slab (32 KB, 64 rows) staged into the union of the 4 waves' Abuf1
// regions (disjoint from Abuf0/chunk0): row r -> lds + (r>>4)*16384 + 8192
// + (r&15)*512. Read into 128 pinned VGPRs, then chunk pipeline.
// Counted vmcnt: 12 = 8 next-chunk loads + 4 stores (in-order decrement).
// LDS swizzle (both-sides): phys 16B-slot s of row r holds logical s^(r&15).
__global__ __launch_bounds__(256, 2) void gemm(const __bf16* __restrict__ xb,
                                               const __bf16* __restrict__ wb,
                                               const float* __restrict__ bias,
                                               float* __restrict__ out) {
    __shared__ __align__(16) char lds[4 * 2 * 8192];  // 4 waves * {Abuf0, Abuf1}

    int bid = blockIdx.x;
    int cp = bid >> 4;           // 0..24
    int rt = bid & (ROWTILES - 1);
    int c0 = cp * 2;
    int row0 = rt * 512;
    int lane = threadIdx.x & 63;
    int w4 = threadIdx.x >> 6;
    int l15 = lane & 15;
    int g = lane >> 4;
    int s31 = lane & 31;
    int lr = lane >> 5;          // 0/1

    char* Abuf0 = lds + w4 * 16384;
    char* Abuf1 = Abuf0 + 8192;

    // --- stage A chunk 0 (wave-private 16 rows = 8 KB) into Abuf0 ---
    const char* arows = (const char*)(xb + (size_t)(row0 + w4 * 128) * IN_DIM);
#define STAGE_A(BUF, CHUNK)                                                       \
    _Pragma("unroll") for (int il = 0; il < 8; ++il) {                            \
        int r = (CHUNK) * 16 + 2 * il + lr;                                       \
        gload_lds16(arows + (size_t)r * 512 + ((s31 ^ (r & 15)) * 16),            \
                    (BUF) + il * 1024);                                           \
    }
    STAGE_A(Abuf0, 0)

    // --- stage W' pair (32 KB = 64 rows) into the Abuf1 regions ---
    const char* wsrc = (const char*)(wb + (size_t)c0 * OUT_DIM * IN_DIM);
#pragma unroll
    for (int jw = 0; jw < 8; ++jw) {
        int re = jw * 8 + w4 * 2;              // even row of this instr
        int r = re + lr;
        gload_lds16(wsrc + (size_t)r * 512 + ((s31 ^ (r & 15)) * 16),
                    lds + (re >> 4) * 16384 + 8192 + (re & 15) * 512);
    }

    asm volatile("s_waitcnt vmcnt(0)" ::: "memory");
    __syncthreads();
    __builtin_amdgcn_sched_barrier(0);

    // --- W' -> regs (swizzled ds_read); W row = ci*32 + l15 (+16) ---
    bf16x8 W[2][16];
#pragma unroll
    for (int ci = 0; ci < 2; ++ci)
#pragma unroll
        for (int kk = 0; kk < 8; ++kk) {
            int slot = (4 * kk + g) ^ l15;
            W[ci][kk]     = *reinterpret_cast<const bf16x8*>(
                lds + (2 * ci) * 16384 + 8192 + l15 * 512 + slot * 16);
            W[ci][8 + kk] = *reinterpret_cast<const bf16x8*>(
                lds + (2 * ci + 1) * 16384 + 8192 + l15 * 512 + slot * 16);
        }
#pragma unroll
    for (int ci = 0; ci < 2; ++ci)
#pragma unroll
        for (int kk = 0; kk < 16; ++kk)
            asm volatile("" : "+v"(W[ci][kk]));
    __builtin_amdgcn_sched_barrier(0);
    __syncthreads();   // all waves done reading W before chunk 1 stages Abuf1

    f32x4 bv00 = *reinterpret_cast<const f32x4*>(bias + c0 * OUT_DIM + g * 4);
    f32x4 bv01 = *reinterpret_cast<const f32x4*>(bias + c0 * OUT_DIM + 16 + g * 4);
    f32x4 bv10 = *reinterpret_cast<const f32x4*>(bias + (c0 + 1) * OUT_DIM + g * 4);
    f32x4 bv11 = *reinterpret_cast<const f32x4*>(bias + (c0 + 1) * OUT_DIM + 16 + g * 4);

    float* orow = out + (size_t)(row0 + w4 * 128 + l15) * (NCLS * OUT_DIM) + c0 * OUT_DIM + g * 4;

    // --- main loop: 8 chunks of 16 rows, 2 classes each ---
#pragma unroll
    for (int k = 0; k < NCHUNK; ++k) {
        char* cur = (k & 1) ? Abuf1 : Abuf0;
        char* nxt = (k & 1) ? Abuf0 : Abuf1;
        if (k + 1 < NCHUNK) {
            STAGE_A(nxt, k + 1)
            asm volatile("s_waitcnt vmcnt(12)" ::: "memory");
        } else {
            asm volatile("s_waitcnt vmcnt(4)" ::: "memory");
        }
        __builtin_amdgcn_sched_barrier(0);

        f32x4 acc00 = bv00;
        f32x4 acc01 = bv01;
        f32x4 acc10 = bv10;
        f32x4 acc11 = bv11;
#pragma unroll
        for (int kk = 0; kk < 8; ++kk) {
            int slot = (4 * kk + g) ^ l15;
            bf16x8 a = *reinterpret_cast<const bf16x8*>(cur + (size_t)l15 * 512 + slot * 16);
            acc00 = __builtin_amdgcn_mfma_f32_16x16x32_bf16(W[0][kk],     a, acc00, 0, 0, 0);
            acc01 = __builtin_amdgcn_mfma_f32_16x16x32_bf16(W[0][8 + kk], a, acc01, 0, 0, 0);
            acc10 = __builtin_amdgcn_mfma_f32_16x16x32_bf16(W[1][kk],     a, acc10, 0, 0, 0);
            acc11 = __builtin_amdgcn_mfma_f32_16x16x32_bf16(W[1][8 + kk], a, acc11, 0, 0, 0);
        }
        float* op = orow + (size_t)k * 16 * (NCLS * OUT_DIM);
        *reinterpret_cast<f32x4*>(op) = acc00;
        *reinterpret_cast<f32x4*>(op + 16) = acc01;
        *reinterpret_cast<f32x4*>(op + OUT_DIM) = acc10;
        *reinterpret_cast<f32x4*>(op + OUT_DIM + 16) = acc11;
    }
#undef STAGE_A
}

extern "C" void kernel_launch(void* const* d_in, const int* in_sizes, int n_in,
                              void* d_out, int out_size, void* d_ws, size_t ws_size,
                              hipStream_t stream) {
    const float* x    = (const float*)d_in[0];
    const float* w    = (const float*)d_in[1];
    const float* bias = (const float*)d_in[2];
    float* out = (float*)d_out;

    __bf16* xb = (__bf16*)d_ws;                      // 8192*256 bf16 = 4 MB
    __bf16* wb = xb + (size_t)B_ROWS * IN_DIM;       // 50*32*256 bf16 = 0.8 MB

    prep<<<NCLS + CVT_BLOCKS, 256, 0, stream>>>(x, w, xb, wb);
    gemm<<<25 * ROWTILES, 256, 0, stream>>>(xb, wb, bias, out);
}